// Round 3
// baseline (885.429 us; speedup 1.0000x reference)
//
#include <hip/hip_runtime.h>

namespace {

constexpr int kS = 1024;
constexpr int kD = 64;
constexpr int kH = 128;

__device__ __forceinline__ float fast_tanh(float x) {
  x = fminf(fmaxf(x, -15.f), 15.f);
  float e = __expf(2.f * x);
  return (e - 1.f) * __builtin_amdgcn_rcpf(e + 1.f);
}

__device__ __forceinline__ float dot4(float4 w, float4 v, float a) {
  a = fmaf(w.x, v.x, a);
  a = fmaf(w.y, v.y, a);
  a = fmaf(w.z, v.z, a);
  return fmaf(w.w, v.w, a);
}

__device__ __forceinline__ float lane_xor4(float v) {
  return __int_as_float(__builtin_amdgcn_ds_swizzle(__float_as_int(v), 0x101F));
}
#if __has_builtin(__builtin_amdgcn_mov_dpp)
__device__ __forceinline__ float lane_xor2(float v) {
  return __int_as_float(__builtin_amdgcn_mov_dpp(__float_as_int(v), 0x4E, 0xF, 0xF, true));
}
__device__ __forceinline__ float lane_xor1(float v) {
  return __int_as_float(__builtin_amdgcn_mov_dpp(__float_as_int(v), 0xB1, 0xF, 0xF, true));
}
#else
__device__ __forceinline__ float lane_xor2(float v) {
  return __int_as_float(__builtin_amdgcn_ds_swizzle(__float_as_int(v), 0x081F));
}
__device__ __forceinline__ float lane_xor1(float v) {
  return __int_as_float(__builtin_amdgcn_ds_swizzle(__float_as_int(v), 0x041F));
}
#endif
__device__ __forceinline__ float swz_xor1(float v) {
  return __int_as_float(__builtin_amdgcn_ds_swizzle(__float_as_int(v), 0x041F));
}
__device__ __forceinline__ float swz_xor2(float v) {
  return __int_as_float(__builtin_amdgcn_ds_swizzle(__float_as_int(v), 0x081F));
}

// ---- xp element codecs: fp32 (preferred) or bf16 (small-ws fallback) ----
struct XpF32 {
  using T = float;
  using V = float4;
  static __device__ __forceinline__ T enc(float f) { return f; }
  static __device__ __forceinline__ float4 dec(V v) { return v; }
};
struct XpBf16 {
  using T = unsigned short;
  using V = ushort4;
  static __device__ __forceinline__ T enc(float f) {
    unsigned u = __float_as_uint(f);
    u += 0x7FFF + ((u >> 16) & 1);  // RNE
    return (unsigned short)(u >> 16);
  }
  static __device__ __forceinline__ float4 dec(V v) {
    return make_float4(__uint_as_float((unsigned)v.x << 16),
                       __uint_as_float((unsigned)v.y << 16),
                       __uint_as_float((unsigned)v.z << 16),
                       __uint_as_float((unsigned)v.w << 16));
  }
};

// =====================  Phase A: x-projection GEMM  =====================
// xp[dir][b][j][t'] = Wih_dir[j,:].x[b,t,:] + bih+bhh, with t' time-reversed
// for dir=1 so phase B reads linearly in step order.
// Block: (b, t-quarter). Thread owns one t; x row in 16 f4 regs; W in LDS
// (broadcast reads). 2 blocks/CU, compute-bound at fp32 vector rate.
template <class XP>
__global__ __launch_bounds__(256, 2) void xproj_kernel(
    const float* __restrict__ inputs,
    const float* __restrict__ Wih_fw, const float* __restrict__ bih_fw,
    const float* __restrict__ bhh_fw,
    const float* __restrict__ Wih_bw, const float* __restrict__ bih_bw,
    const float* __restrict__ bhh_bw,
    typename XP::T* __restrict__ xp) {
  __shared__ float Wl[2 * kH * kD];  // 64 KB
  __shared__ float bl[2 * kH];
  const int tid = threadIdx.x;
  const int b = blockIdx.x >> 2;
  const int t = (blockIdx.x & 3) * 256 + tid;

  {
    const float4* s0 = (const float4*)Wih_fw;
    const float4* s1 = (const float4*)Wih_bw;
    float4* d = (float4*)Wl;
#pragma unroll
    for (int k = 0; k < 8; ++k) d[tid + k * 256] = s0[tid + k * 256];
#pragma unroll
    for (int k = 0; k < 8; ++k) d[2048 + tid + k * 256] = s1[tid + k * 256];
  }
  if (tid < kH) bl[tid] = bih_fw[tid] + bhh_fw[tid];
  else bl[tid] = bih_bw[tid - kH] + bhh_bw[tid - kH];
  __syncthreads();

  float4 xv[16];
  const float4* xr = (const float4*)(inputs + ((size_t)b * kS + t) * kD);
#pragma unroll
  for (int k = 0; k < 16; ++k) xv[k] = xr[k];

#pragma unroll 2
  for (int jd = 0; jd < 256; ++jd) {
    const float4* wp = (const float4*)&Wl[jd * kD];
    float a0 = bl[jd], a1 = 0.f, a2 = 0.f, a3 = 0.f;
#pragma unroll
    for (int k = 0; k < 16; k += 4) {
      a0 = dot4(wp[k + 0], xv[k + 0], a0);
      a1 = dot4(wp[k + 1], xv[k + 1], a1);
      a2 = dot4(wp[k + 2], xv[k + 2], a2);
      a3 = dot4(wp[k + 3], xv[k + 3], a3);
    }
    const float acc = (a0 + a1) + (a2 + a3);
    const int dir = jd >> 7, j = jd & 127;
    const int tt = dir ? (kS - 1 - t) : t;
    xp[(((size_t)dir * 256 + b) * kH + j) * kS + tt] = XP::enc(acc);
  }
}

#define FOREACH_M(F) F(0) F(1) F(2) F(3) F(4) F(5) F(6) F(7)

// =====================  Phase B: persistent recurrence  =====================
// grid 512: dir = blockIdx>>8, b = blockIdx&255; one (dir,b) row per block.
// block 128: g = tid>>3 (16 groups), p = tid&7 (K slice of 16).
// Thread holds Whh[g+16m][16p..16p+16) for m=0..7: 32 float4 = 128 VGPRs —
// total demand ~170 < 256 arch cap (R2's 192-float tile spilled to AGPRs).
// Per step: 4 conflict-free ds_read_b128 (h slice), 128 FMAs, 3-stage
// butterfly over p; lane p finalizes j = g+16p; xp prefetched 2 quads ahead.
template <class XP>
__global__ __launch_bounds__(128, 2) void birnn_step_kernel(
    const typename XP::T* __restrict__ xp,
    const float* __restrict__ Whh_fw, const float* __restrict__ Whh_bw,
    const float* __restrict__ fcW, const float* __restrict__ fcb,
    float* __restrict__ out) {
  const int dir = blockIdx.x >> 8;
  const int b = blockIdx.x & 255;
  const int tid = threadIdx.x;
  const int g = tid >> 3;
  const int p = tid & 7;

  const float* __restrict__ Whh = dir ? Whh_bw : Whh_fw;

  // h: 8 slices of 16 floats padded to 20 (start banks p*20%32 all distinct,
  // disjoint 4-bank spans per b128 -> conflict-free, 8-lane broadcast).
  __shared__ float hbuf[2][160];
  __shared__ float fcwl[kH];
  __shared__ float hh[32][132];  // 32-step journal (132*4=528B rows, 16B aligned)

#define DECLS(m) float4 wh0_##m, wh1_##m, wh2_##m, wh3_##m;
  FOREACH_M(DECLS)
#undef DECLS
#define LOADS(m)                                                          \
  {                                                                       \
    const float4* wp = (const float4*)(Whh + (g + 16 * m) * kH + 16 * p); \
    wh0_##m = wp[0]; wh1_##m = wp[1]; wh2_##m = wp[2]; wh3_##m = wp[3];   \
  }
  FOREACH_M(LOADS)
#undef LOADS

  const int jfin = g + 16 * p;
  const float fcb0 = fcb[0];
  fcwl[tid] = fcW[dir * kH + tid];
  hbuf[0][p * 20 + g] = 0.f;

  // xp quad stream for this lane's output row
  using V = typename XP::V;
  const V* xrow = (const V*)(xp + (((size_t)dir * 256 + b) * kH + jfin) * kS);
  V xA = xrow[0];
  V xB = xrow[1];
  __syncthreads();

  for (int i4 = 0; i4 < 256; ++i4) {
    // fc drain for steps i4*4-32 .. i4*4-1 (journal slots about to be reused)
    if ((i4 & 7) == 0 && i4) {
      const int c = tid >> 2, kp = tid & 3;
      float v = 0.f;
      const float4* jp = (const float4*)&hh[c][kp * 32];
      const float4* fp = (const float4*)&fcwl[kp * 32];
#pragma unroll
      for (int k4 = 0; k4 < 8; ++k4) v = dot4(fp[k4], jp[k4], v);
      v += swz_xor1(v);
      v += swz_xor2(v);
      if (kp == 0) {
        const int ii = i4 * 4 - 32 + c;
        const int td = dir ? (kS - 1 - ii) : ii;
        if (dir == 0) v += fcb0;
        atomicAdd(&out[(size_t)b * kS + td], v);
      }
      __syncthreads();  // drain reads done before journal slots rewritten
    }

    V xN = (i4 < 254) ? xrow[i4 + 2] : xB;
    const float4 xq = XP::dec(xA);

#pragma unroll
    for (int q = 0; q < 4; ++q) {
      const int i = i4 * 4 + q;
      const float xpv = q == 0 ? xq.x : q == 1 ? xq.y : q == 2 ? xq.z : xq.w;

      const float4* hp = (const float4*)(&hbuf[i & 1][0] + p * 20);
      const float4 h0 = hp[0], h1 = hp[1], h2 = hp[2], h3 = hp[3];
#define COMP(m)                                  \
  float s_##m = dot4(wh3_##m, h3,                \
                dot4(wh2_##m, h2,                \
                dot4(wh1_##m, h1,                \
                dot4(wh0_##m, h0, 0.f))));
      FOREACH_M(COMP)
#undef COMP
      const bool hi4 = (p & 4) != 0, hi2 = (p & 2) != 0, hi1 = (p & 1) != 0;
      float k0 = (hi4 ? s_4 : s_0) + lane_xor4(hi4 ? s_0 : s_4);
      float k1 = (hi4 ? s_5 : s_1) + lane_xor4(hi4 ? s_1 : s_5);
      float k2 = (hi4 ? s_6 : s_2) + lane_xor4(hi4 ? s_2 : s_6);
      float k3 = (hi4 ? s_7 : s_3) + lane_xor4(hi4 ? s_3 : s_7);
      float n0 = (hi2 ? k2 : k0) + lane_xor2(hi2 ? k0 : k2);
      float n1 = (hi2 ? k3 : k1) + lane_xor2(hi2 ? k1 : k3);
      float v = (hi1 ? n1 : n0) + lane_xor1(hi1 ? n0 : n1);

      const float hn = fast_tanh(v + xpv);
      hbuf[(i & 1) ^ 1][p * 20 + g] = hn;
      hh[i & 31][jfin] = hn;
      __syncthreads();  // end-of-step: h + journal visible for next step/drain
    }
    xA = xB;
    xB = xN;
  }

  // final fc drain: steps S-32..S-1
  {
    const int c = tid >> 2, kp = tid & 3;
    float v = 0.f;
    const float4* jp = (const float4*)&hh[c][kp * 32];
    const float4* fp = (const float4*)&fcwl[kp * 32];
#pragma unroll
    for (int k4 = 0; k4 < 8; ++k4) v = dot4(fp[k4], jp[k4], v);
    v += swz_xor1(v);
    v += swz_xor2(v);
    if (kp == 0) {
      const int ii = kS - 32 + c;
      const int td = dir ? (kS - 1 - ii) : ii;
      if (dir == 0) v += fcb0;
      atomicAdd(&out[(size_t)b * kS + td], v);
    }
  }
}

#undef FOREACH_M

}  // namespace

extern "C" void kernel_launch(void* const* d_in, const int* in_sizes, int n_in,
                              void* d_out, int out_size, void* d_ws, size_t ws_size,
                              hipStream_t stream) {
  (void)in_sizes; (void)n_in;
  const float* inputs = (const float*)d_in[0];
  const float* Wih_fw = (const float*)d_in[1];
  const float* Whh_fw = (const float*)d_in[2];
  const float* bih_fw = (const float*)d_in[3];
  const float* bhh_fw = (const float*)d_in[4];
  const float* Wih_bw = (const float*)d_in[5];
  const float* Whh_bw = (const float*)d_in[6];
  const float* bih_bw = (const float*)d_in[7];
  const float* bhh_bw = (const float*)d_in[8];
  const float* fc_W   = (const float*)d_in[9];
  const float* fc_b   = (const float*)d_in[10];
  float* out = (float*)d_out;

  hipMemsetAsync(out, 0, (size_t)out_size * sizeof(float), stream);

  const size_t xp_elems = 2ull * 256 * kH * kS;  // 67,108,864
  const bool use_f32 = ws_size >= xp_elems * sizeof(float);

  dim3 gridA(1024), blockA(256), gridB(512), blockB(128);
  if (use_f32) {
    hipLaunchKernelGGL((xproj_kernel<XpF32>), gridA, blockA, 0, stream,
                       inputs, Wih_fw, bih_fw, bhh_fw, Wih_bw, bih_bw, bhh_bw,
                       (float*)d_ws);
    hipLaunchKernelGGL((birnn_step_kernel<XpF32>), gridB, blockB, 0, stream,
                       (const float*)d_ws, Whh_fw, Whh_bw, fc_W, fc_b, out);
  } else {
    hipLaunchKernelGGL((xproj_kernel<XpBf16>), gridA, blockA, 0, stream,
                       inputs, Wih_fw, bih_fw, bhh_fw, Wih_bw, bih_bw, bhh_bw,
                       (unsigned short*)d_ws);
    hipLaunchKernelGGL((birnn_step_kernel<XpBf16>), gridB, blockB, 0, stream,
                       (const unsigned short*)d_ws, Whh_fw, Whh_bw, fc_W, fc_b, out);
  }
}

// Round 4
// 843.955 us; speedup vs baseline: 1.0491x; 1.0491x over previous
//
#include <hip/hip_runtime.h>

namespace {

constexpr int kS = 1024;
constexpr int kD = 64;
constexpr int kH = 128;

typedef __attribute__((ext_vector_type(2))) float f32x2;

__device__ __forceinline__ f32x2 pkfma(f32x2 a, f32x2 b, f32x2 c) {
  f32x2 d;
  asm("v_pk_fma_f32 %0, %1, %2, %3" : "=v"(d) : "v"(a), "v"(b), "v"(c));
  return d;
}
__device__ __forceinline__ f32x2 pkmul(f32x2 a, f32x2 b) {
  f32x2 d;
  asm("v_pk_mul_f32 %0, %1, %2" : "=v"(d) : "v"(a), "v"(b));
  return d;
}
__device__ __forceinline__ f32x2 lo2(float4 v) { f32x2 r; r.x = v.x; r.y = v.y; return r; }
__device__ __forceinline__ f32x2 hi2(float4 v) { f32x2 r; r.x = v.z; r.y = v.w; return r; }

__device__ __forceinline__ float fast_tanh(float x) {
  x = fminf(fmaxf(x, -15.f), 15.f);
  float e = __expf(2.f * x);
  return (e - 1.f) * __builtin_amdgcn_rcpf(e + 1.f);
}

__device__ __forceinline__ float dot4(float4 w, float4 v, float a) {
  a = fmaf(w.x, v.x, a);
  a = fmaf(w.y, v.y, a);
  a = fmaf(w.z, v.z, a);
  return fmaf(w.w, v.w, a);
}

__device__ __forceinline__ float lane_xor4(float v) {
  return __int_as_float(__builtin_amdgcn_ds_swizzle(__float_as_int(v), 0x101F));
}
__device__ __forceinline__ float lane_xor2(float v) {
  return __int_as_float(__builtin_amdgcn_mov_dpp(__float_as_int(v), 0x4E, 0xF, 0xF, true));
}
__device__ __forceinline__ float lane_xor1(float v) {
  return __int_as_float(__builtin_amdgcn_mov_dpp(__float_as_int(v), 0xB1, 0xF, 0xF, true));
}
__device__ __forceinline__ float swz_xor1(float v) {
  return __int_as_float(__builtin_amdgcn_ds_swizzle(__float_as_int(v), 0x041F));
}
__device__ __forceinline__ float swz_xor2(float v) {
  return __int_as_float(__builtin_amdgcn_ds_swizzle(__float_as_int(v), 0x081F));
}

// xp element codecs
struct XpF32 {
  using T = float;
  static __device__ __forceinline__ T enc(float f) { return f; }
  static __device__ __forceinline__ float dec1(T v) { return v; }
};
struct XpBf16 {
  using T = unsigned short;
  static __device__ __forceinline__ T enc(float f) {
    unsigned u = __float_as_uint(f);
    u += 0x7FFF + ((u >> 16) & 1);  // RNE
    return (unsigned short)(u >> 16);
  }
  static __device__ __forceinline__ float dec1(T v) {
    return __uint_as_float((unsigned)v << 16);
  }
};

// xp layout (per (dir,b) slab of kS*kH elements), chunk-transposed for phase B:
//   idx = (t>>5)*(kH*32) + j*32 + (t&31)
// Phase B stages one 32-step chunk (4096 elems) at a time, lane-ordered.

// =====================  Phase A: x-projection, no LDS  =====================
// Thread owns one t: x row in 16 f4 regs; W/bias via wave-uniform s_loads
// (broadcast, zero LDS traffic). 4 blocks/CU -> 4 waves/SIMD. VALU-bound.
template <class XP>
__global__ __launch_bounds__(256, 4) void xproj_kernel(
    const float* __restrict__ inputs,
    const float* __restrict__ Wih_fw, const float* __restrict__ bih_fw,
    const float* __restrict__ bhh_fw,
    const float* __restrict__ Wih_bw, const float* __restrict__ bih_bw,
    const float* __restrict__ bhh_bw,
    typename XP::T* __restrict__ xp) {
  const int b = blockIdx.x >> 2;
  const int t = (blockIdx.x & 3) * 256 + threadIdx.x;

  float4 xv[16];
  const float4* xr = (const float4*)(inputs + ((size_t)b * kS + t) * kD);
#pragma unroll
  for (int k = 0; k < 16; ++k) xv[k] = xr[k];

#pragma unroll 1
  for (int dir = 0; dir < 2; ++dir) {
    const float* __restrict__ W  = dir ? Wih_bw : Wih_fw;
    const float* __restrict__ bi = dir ? bih_bw : bih_fw;
    const float* __restrict__ bh = dir ? bhh_bw : bhh_fw;
    const int tt = dir ? (kS - 1 - t) : t;
    typename XP::T* dst = xp + ((size_t)(dir * 256 + b)) * (kS * kH) +
                          (size_t)(tt >> 5) * (kH * 32) + (tt & 31);
#pragma unroll 2
    for (int j = 0; j < kH; ++j) {
      const float4* wr = (const float4*)(W + j * kD);  // wave-uniform -> s_load
      float a0 = 0.f, a1 = 0.f, a2 = 0.f, a3 = 0.f;
#pragma unroll
      for (int k = 0; k < 16; k += 4) {
        a0 = dot4(wr[k + 0], xv[k + 0], a0);
        a1 = dot4(wr[k + 1], xv[k + 1], a1);
        a2 = dot4(wr[k + 2], xv[k + 2], a2);
        a3 = dot4(wr[k + 3], xv[k + 3], a3);
      }
      const float v = (a0 + a1) + (a2 + a3) + bi[j] + bh[j];
      dst[(size_t)j * 32] = XP::enc(v);
    }
  }
}

#define FOREACH_M(F) F(0) F(1) F(2) F(3) F(4) F(5) F(6) F(7)

// =====================  Phase B: persistent recurrence  =====================
// grid 512: dir = blockIdx>>8, b = blockIdx&255. block 128: g=tid>>3, p=tid&7.
// Whh[g+16m][16p..+16) in 32 named float4 (pk_fma asm forces VGPR use;
// waves_per_eu(1) lifts the budget so they stay arch-resident).
// Inner loop is vm-clean: xp double-buffered via LDS 32-step chunks (loads
// issued one chunk early), fc output accumulated in LDS, atomics at end only.
template <class XP>
__global__ __launch_bounds__(128) __attribute__((amdgpu_waves_per_eu(1)))
void birnn_step_kernel(
    const typename XP::T* __restrict__ xp,
    const float* __restrict__ Whh_fw, const float* __restrict__ Whh_bw,
    const float* __restrict__ fcW, const float* __restrict__ fcb,
    float* __restrict__ out) {
  using T = typename XP::T;
  constexpr int NV = (32 * (int)sizeof(T)) / 16;        // uint4 loads per chunk
  constexpr int CSTRIDE = (4096 * (int)sizeof(T)) / 16; // uint4 stride per chunk
  const int dir = blockIdx.x >> 8;
  const int b = blockIdx.x & 255;
  const int tid = threadIdx.x;
  const int g = tid >> 3;
  const int p = tid & 7;
  const int jfin = g + 16 * p;  // output this lane finalizes; also its xq column

  const float* __restrict__ Whh = dir ? Whh_bw : Whh_fw;

  __shared__ float hbuf[2][160];      // h slices padded to 20 (conflict-free b128)
  __shared__ T xq[2][32][kH];         // lane-ordered xp chunks (bank = tid%32)
  __shared__ float hh[32 * 132];      // journal, lane-ordered cols, row pad 132
  __shared__ float fcwl[kH];          // fc weights, lane-ordered
  __shared__ float outrow[kS];        // fc accumulation row

#define DECLS(m) float4 wh0_##m, wh1_##m, wh2_##m, wh3_##m;
  FOREACH_M(DECLS)
#undef DECLS
#define LOADS(m)                                                          \
  {                                                                       \
    const float4* wp = (const float4*)(Whh + (g + 16 * m) * kH + 16 * p); \
    wh0_##m = wp[0]; wh1_##m = wp[1]; wh2_##m = wp[2]; wh3_##m = wp[3];   \
  }
  FOREACH_M(LOADS)
#undef LOADS

  fcwl[tid] = fcW[dir * kH + jfin];  // lane-ordered (matches hh columns)
  hbuf[0][p * 20 + g] = 0.f;

  // xp stream: this lane stages its own row jfin into column tid.
  const uint4* gx = (const uint4*)(xp + ((size_t)(dir * 256 + b)) * (kS * kH) +
                                   (size_t)jfin * 32);
  uint4 r[NV];
#pragma unroll
  for (int k = 0; k < NV; ++k) r[k] = gx[k];  // chunk 0
  {
    T rt[32];
    __builtin_memcpy(rt, r, sizeof(rt));
#pragma unroll
    for (int e = 0; e < 32; ++e) xq[0][e][tid] = rt[e];
  }
#pragma unroll
  for (int k = 0; k < NV; ++k) r[k] = gx[CSTRIDE + k];  // chunk 1 -> regs
  __syncthreads();

  for (int c = 0; c < 32; ++c) {
    const int cur = c & 1;
    if (c < 31) {  // stage chunk c+1 (held in r since entry c-1; loads landed)
      T rt[32];
      __builtin_memcpy(rt, r, sizeof(rt));
#pragma unroll
      for (int e = 0; e < 32; ++e) xq[cur ^ 1][e][tid] = rt[e];
    }
    if (c < 30) {  // issue loads for chunk c+2 (one full chunk of slack)
#pragma unroll
      for (int k = 0; k < NV; ++k) r[k] = gx[(size_t)(c + 2) * CSTRIDE + k];
    }
    if (c > 0) {  // fc drain for chunk c-1 (hh rows about to be reused)
      const int cc = tid >> 2, kp = tid & 3;
      float v = 0.f;
      const float4* jp = (const float4*)&hh[cc * 132 + kp * 32];
      const float4* fp = (const float4*)&fcwl[kp * 32];
#pragma unroll
      for (int k4 = 0; k4 < 8; ++k4) v = dot4(fp[k4], jp[k4], v);
      v += swz_xor1(v);
      v += swz_xor2(v);
      if (kp == 0) outrow[(c - 1) * 32 + cc] = v;
      __syncthreads();
    }

#pragma unroll 2
    for (int cc = 0; cc < 32; ++cc) {
      const int i = c * 32 + cc;
      const float xpv = XP::dec1(xq[cur][cc][tid]);

      const float4* hp = (const float4*)(&hbuf[i & 1][p * 20]);
      const float4 h0 = hp[0], h1 = hp[1], h2 = hp[2], h3 = hp[3];
      const f32x2 hl0 = lo2(h0), hx0 = hi2(h0), hl1 = lo2(h1), hx1 = hi2(h1);
      const f32x2 hl2 = lo2(h2), hx2 = hi2(h2), hl3 = lo2(h3), hx3 = hi2(h3);

#define COMP(m)                                      \
  f32x2 s_##m = pkmul(lo2(wh0_##m), hl0);            \
  s_##m = pkfma(hi2(wh0_##m), hx0, s_##m);           \
  s_##m = pkfma(lo2(wh1_##m), hl1, s_##m);           \
  s_##m = pkfma(hi2(wh1_##m), hx1, s_##m);           \
  s_##m = pkfma(lo2(wh2_##m), hl2, s_##m);           \
  s_##m = pkfma(hi2(wh2_##m), hx2, s_##m);           \
  s_##m = pkfma(lo2(wh3_##m), hl3, s_##m);           \
  s_##m = pkfma(hi2(wh3_##m), hx3, s_##m);           \
  const float v_##m = s_##m.x + s_##m.y;
      FOREACH_M(COMP)
#undef COMP

      const bool hi4b = (p & 4) != 0, hi2b = (p & 2) != 0, hi1b = (p & 1) != 0;
      float k0 = (hi4b ? v_4 : v_0) + lane_xor4(hi4b ? v_0 : v_4);
      float k1 = (hi4b ? v_5 : v_1) + lane_xor4(hi4b ? v_1 : v_5);
      float k2 = (hi4b ? v_6 : v_2) + lane_xor4(hi4b ? v_2 : v_6);
      float k3 = (hi4b ? v_7 : v_3) + lane_xor4(hi4b ? v_3 : v_7);
      float n0 = (hi2b ? k2 : k0) + lane_xor2(hi2b ? k0 : k2);
      float n1 = (hi2b ? k3 : k1) + lane_xor2(hi2b ? k1 : k3);
      float v = (hi1b ? n1 : n0) + lane_xor1(hi1b ? n0 : n1);

      const float hn = fast_tanh(v + xpv);
      hbuf[(i & 1) ^ 1][p * 20 + g] = hn;
      hh[cc * 132 + tid] = hn;  // lane-ordered column
      __syncthreads();
    }
  }

  // final fc drain: chunk 31
  {
    const int cc = tid >> 2, kp = tid & 3;
    float v = 0.f;
    const float4* jp = (const float4*)&hh[cc * 132 + kp * 32];
    const float4* fp = (const float4*)&fcwl[kp * 32];
#pragma unroll
    for (int k4 = 0; k4 < 8; ++k4) v = dot4(fp[k4], jp[k4], v);
    v += swz_xor1(v);
    v += swz_xor2(v);
    if (kp == 0) outrow[992 + cc] = v;
  }
  __syncthreads();

  const float fcb0 = fcb[0];
#pragma unroll
  for (int k = 0; k < 8; ++k) {
    const int t0 = tid + 128 * k;
    float v = outrow[t0];
    if (dir == 0) v += fcb0;
    const int td = dir ? (kS - 1 - t0) : t0;
    atomicAdd(&out[(size_t)b * kS + td], v);
  }
}

#undef FOREACH_M

}  // namespace

extern "C" void kernel_launch(void* const* d_in, const int* in_sizes, int n_in,
                              void* d_out, int out_size, void* d_ws, size_t ws_size,
                              hipStream_t stream) {
  (void)in_sizes; (void)n_in;
  const float* inputs = (const float*)d_in[0];
  const float* Wih_fw = (const float*)d_in[1];
  const float* Whh_fw = (const float*)d_in[2];
  const float* bih_fw = (const float*)d_in[3];
  const float* bhh_fw = (const float*)d_in[4];
  const float* Wih_bw = (const float*)d_in[5];
  const float* Whh_bw = (const float*)d_in[6];
  const float* bih_bw = (const float*)d_in[7];
  const float* bhh_bw = (const float*)d_in[8];
  const float* fc_W   = (const float*)d_in[9];
  const float* fc_b   = (const float*)d_in[10];
  float* out = (float*)d_out;

  hipMemsetAsync(out, 0, (size_t)out_size * sizeof(float), stream);

  const size_t xp_elems = 2ull * 256 * kH * kS;
  const bool use_f32 = ws_size >= xp_elems * sizeof(float);

  dim3 gridA(1024), blockA(256), gridB(512), blockB(128);
  if (use_f32) {
    hipLaunchKernelGGL((xproj_kernel<XpF32>), gridA, blockA, 0, stream,
                       inputs, Wih_fw, bih_fw, bhh_fw, Wih_bw, bih_bw, bhh_bw,
                       (float*)d_ws);
    hipLaunchKernelGGL((birnn_step_kernel<XpF32>), gridB, blockB, 0, stream,
                       (const float*)d_ws, Whh_fw, Whh_bw, fc_W, fc_b, out);
  } else {
    hipLaunchKernelGGL((xproj_kernel<XpBf16>), gridA, blockA, 0, stream,
                       inputs, Wih_fw, bih_fw, bhh_fw, Wih_bw, bih_bw, bhh_bw,
                       (unsigned short*)d_ws);
    hipLaunchKernelGGL((birnn_step_kernel<XpBf16>), gridB, blockB, 0, stream,
                       (const unsigned short*)d_ws, Whh_fw, Whh_bw, fc_W, fc_b, out);
  }
}

// Round 5
// 795.857 us; speedup vs baseline: 1.1125x; 1.0604x over previous
//
#include <hip/hip_runtime.h>

namespace {

constexpr int kS = 1024;
constexpr int kD = 64;
constexpr int kH = 128;

typedef __attribute__((ext_vector_type(2))) float f32x2;
typedef __attribute__((ext_vector_type(4))) float f32x4;
typedef __attribute__((ext_vector_type(8))) _Float16 half8;

__device__ __forceinline__ f32x2 pkfma(f32x2 a, f32x2 b, f32x2 c) {
  f32x2 d;
  asm("v_pk_fma_f32 %0, %1, %2, %3" : "=v"(d) : "v"(a), "v"(b), "v"(c));
  return d;
}
__device__ __forceinline__ f32x2 pkmul(f32x2 a, f32x2 b) {
  f32x2 d;
  asm("v_pk_mul_f32 %0, %1, %2" : "=v"(d) : "v"(a), "v"(b));
  return d;
}
__device__ __forceinline__ f32x2 lo2(float4 v) { f32x2 r; r.x = v.x; r.y = v.y; return r; }
__device__ __forceinline__ f32x2 hi2(float4 v) { f32x2 r; r.x = v.z; r.y = v.w; return r; }

__device__ __forceinline__ float fast_tanh(float x) {
  x = fminf(fmaxf(x, -15.f), 15.f);
  float e = __expf(2.f * x);
  return (e - 1.f) * __builtin_amdgcn_rcpf(e + 1.f);
}

__device__ __forceinline__ float dot4(float4 w, float4 v, float a) {
  a = fmaf(w.x, v.x, a);
  a = fmaf(w.y, v.y, a);
  a = fmaf(w.z, v.z, a);
  return fmaf(w.w, v.w, a);
}

// cross-lane: xor1/xor2 via DPP (VALU pipe), xor4/xor8 via ds_swizzle BitMode.
#if __has_builtin(__builtin_amdgcn_mov_dpp)
__device__ __forceinline__ float lane_xor1(float v) {
  return __int_as_float(__builtin_amdgcn_mov_dpp(__float_as_int(v), 0xB1, 0xF, 0xF, true));
}
__device__ __forceinline__ float lane_xor2(float v) {
  return __int_as_float(__builtin_amdgcn_mov_dpp(__float_as_int(v), 0x4E, 0xF, 0xF, true));
}
#else
__device__ __forceinline__ float lane_xor1(float v) {
  return __int_as_float(__builtin_amdgcn_ds_swizzle(__float_as_int(v), 0x041F));
}
__device__ __forceinline__ float lane_xor2(float v) {
  return __int_as_float(__builtin_amdgcn_ds_swizzle(__float_as_int(v), 0x081F));
}
#endif
__device__ __forceinline__ float lane_xor4(float v) {
  return __int_as_float(__builtin_amdgcn_ds_swizzle(__float_as_int(v), 0x101F));
}
__device__ __forceinline__ float lane_xor8(float v) {
  return __int_as_float(__builtin_amdgcn_ds_swizzle(__float_as_int(v), 0x201F));
}
__device__ __forceinline__ float swz_xor1(float v) {
  return __int_as_float(__builtin_amdgcn_ds_swizzle(__float_as_int(v), 0x041F));
}
__device__ __forceinline__ float swz_xor2(float v) {
  return __int_as_float(__builtin_amdgcn_ds_swizzle(__float_as_int(v), 0x081F));
}

// xp (f16) global layout per (dir,b) slab of kS*kH elems, chunk-transposed:
//   idx = (t>>5)*(32*kH) + (t&31)*kH + j      (dir=1 pre-time-reversed)
// so a 32-step chunk is one contiguous 8 KB block, directly LDS-stageable.

// =====================  Phase A: x-projection via f16 MFMA  =====================
// One block per b. M=1024 (t, 8 chunks of 128), N=256 (dir*128+j), K=64.
// mfma_f32_16x16x32_f16; A/B frag: [m|n = lane&15][k = (lane>>4)*8 + e],
// C/D: col=lane&15 (n), row=(lane>>4)*4+reg (m).
__global__ __launch_bounds__(256, 2) void xproj_kernel(
    const float* __restrict__ inputs,
    const float* __restrict__ Wih_fw, const float* __restrict__ bih_fw,
    const float* __restrict__ bhh_fw,
    const float* __restrict__ Wih_bw, const float* __restrict__ bih_bw,
    const float* __restrict__ bhh_bw,
    _Float16* __restrict__ xp) {
  __shared__ _Float16 Wl[256 * 80];   // row pad 80: 2-way banks only
  __shared__ _Float16 xl[128 * 80];
  __shared__ float biasl[256];

  const int tid = threadIdx.x;
  const int b = blockIdx.x;
  const int w = tid >> 6;        // wave id: owns N-tiles 4w..4w+3
  const int lane = tid & 63;
  const int n16 = lane & 15;
  const int q = lane >> 4;

  // ---- stage W (once): thread = one jd row (64 fp32 -> 64 f16) ----
  {
    const int jd = tid;
    const float* src = (jd < kH) ? (Wih_fw + jd * kD) : (Wih_bw + (jd - kH) * kD);
    const float4* s4 = (const float4*)src;
#pragma unroll
    for (int k = 0; k < 8; ++k) {
      float4 a = s4[2 * k], c = s4[2 * k + 1];
      half8 h;
      h[0] = (_Float16)a.x; h[1] = (_Float16)a.y; h[2] = (_Float16)a.z; h[3] = (_Float16)a.w;
      h[4] = (_Float16)c.x; h[5] = (_Float16)c.y; h[6] = (_Float16)c.z; h[7] = (_Float16)c.w;
      *(half8*)&Wl[jd * 80 + k * 8] = h;
    }
    biasl[jd] = (jd < kH) ? (bih_fw[jd] + bhh_fw[jd])
                          : (bih_bw[jd - kH] + bhh_bw[jd - kH]);
  }

  for (int ch = 0; ch < 8; ++ch) {
    __syncthreads();  // previous chunk's xl reads done
    // ---- stage x chunk: thread = (t-row, k-half) ----
    {
      const int tl = tid >> 1, hf = tid & 1;
      const float4* s4 = (const float4*)(inputs +
          ((size_t)b * kS + ch * 128 + tl) * kD + hf * 32);
#pragma unroll
      for (int k = 0; k < 4; ++k) {
        float4 a = s4[2 * k], c = s4[2 * k + 1];
        half8 h;
        h[0] = (_Float16)a.x; h[1] = (_Float16)a.y; h[2] = (_Float16)a.z; h[3] = (_Float16)a.w;
        h[4] = (_Float16)c.x; h[5] = (_Float16)c.y; h[6] = (_Float16)c.z; h[7] = (_Float16)c.w;
        *(half8*)&xl[tl * 80 + hf * 32 + k * 8] = h;
      }
    }
    __syncthreads();

    // ---- B-frags for this wave's 4 N-tiles (held in regs) ----
    half8 bf0[4], bf1[4];
    float bs[4];
#pragma unroll
    for (int nn = 0; nn < 4; ++nn) {
      const int jd = (w * 4 + nn) * 16 + n16;
      bf0[nn] = *(const half8*)&Wl[jd * 80 + q * 8];
      bf1[nn] = *(const half8*)&Wl[jd * 80 + q * 8 + 32];
      bs[nn] = biasl[jd];
    }

#pragma unroll 2
    for (int m = 0; m < 8; ++m) {
      const int trow = m * 16 + n16;
      const half8 a0 = *(const half8*)&xl[trow * 80 + q * 8];
      const half8 a1 = *(const half8*)&xl[trow * 80 + q * 8 + 32];
#pragma unroll
      for (int nn = 0; nn < 4; ++nn) {
        f32x4 acc = {0.f, 0.f, 0.f, 0.f};
        acc = __builtin_amdgcn_mfma_f32_16x16x32_f16(a0, bf0[nn], acc, 0, 0, 0);
        acc = __builtin_amdgcn_mfma_f32_16x16x32_f16(a1, bf1[nn], acc, 0, 0, 0);
        const int jd = (w * 4 + nn) * 16 + n16;
        const int dir = jd >> 7, j = jd & 127;
        const size_t slab = (size_t)(dir * 256 + b) * (kS * kH);
#pragma unroll
        for (int r = 0; r < 4; ++r) {
          const int t = ch * 128 + m * 16 + q * 4 + r;
          const int tt = dir ? (kS - 1 - t) : t;
          xp[slab + (size_t)(tt >> 5) * (32 * kH) + (tt & 31) * kH + j] =
              (_Float16)(acc[r] + bs[nn]);
        }
      }
    }
  }
}

#define FOREACH_M(F) F(0) F(1) F(2) F(3) F(4) F(5) F(6) F(7)

// =====================  Phase B: persistent recurrence  =====================
// 256 blocks: dir = bi>>7, batch pair b0 = (bi&127)*2. 256 threads = 4 waves,
// TWO recurrences per block (rows b0, b0+1) -> 2x in-wave ILP at 1 wave/SIMD.
// Lane: gq = tid>>4 (j-group), p = tid&15 (K-slice of 8). Weights:
// Whh[gq+16m][8p..8p+8) for m=0..7 -> 16 float4 = 64 VGPRs (shared by both rows).
// waves_per_eu(1,1): force 1 wave/EU -> full register budget (anti-AGPR-shunt).
__global__ __launch_bounds__(256) __attribute__((amdgpu_waves_per_eu(1, 1)))
void birnn_step_kernel(
    const _Float16* __restrict__ xp,
    const float* __restrict__ Whh_fw, const float* __restrict__ Whh_bw,
    const float* __restrict__ fcW, const float* __restrict__ fcb,
    float* __restrict__ out) {
  const int bi = blockIdx.x;
  const int dir = bi >> 7;
  const int b0 = (bi & 127) * 2;
  const int tid = threadIdx.x;
  const int gq = tid >> 4;
  const int p = tid & 15;
  const int pm = p & 7;
  const int jfin = gq + 16 * pm;            // output after butterfly (dup p>=8)
  const int haddr = (jfin >> 3) * 12 + (jfin & 7);
  const int slot = gq * 8 + pm;             // journal slot (p<8 only)

  const float* __restrict__ Whh = dir ? Whh_bw : Whh_fw;

  __shared__ float hbuf[2][2][192];         // [parity][row][16 slices * pad12]
  __shared__ _Float16 xq[2][2][4096];       // [buf][row][ (t&31)*128 + j ]
  __shared__ float hhj[2][32][136];         // journal [row][step][slot pad136]
  __shared__ float fcwl[kH];                // fc weights in slot order
  __shared__ float outrow[2][kS];

#define DECLS(m) float4 w0_##m, w1_##m;
  FOREACH_M(DECLS)
#undef DECLS
#define LOADS(m)                                                           \
  {                                                                        \
    const float4* wp = (const float4*)(Whh + (gq + 16 * m) * kH + 8 * p);  \
    w0_##m = wp[0];                                                        \
    w1_##m = wp[1];                                                        \
  }
  FOREACH_M(LOADS)
#undef LOADS

  if (tid < kH) {
    const int s = tid;
    fcwl[s] = fcW[dir * kH + ((s >> 3) + 16 * (s & 7))];
  }
  if (tid < 192) {
    hbuf[0][0][tid] = 0.f;
    hbuf[0][1][tid] = 0.f;
  }

  // ---- xp chunk streaming: thread stages row r_ = tid>>7, 4 uint4/chunk ----
  const int r_ = tid >> 7;
  const int ul = tid & 127;
  const uint4* gb = (const uint4*)(xp + (size_t)(dir * 256 + b0 + r_) * (kS * kH));
  uint4 rv[4];
#pragma unroll
  for (int k = 0; k < 4; ++k) rv[k] = gb[ul + 128 * k];  // chunk 0
  {
    uint4* d = (uint4*)&xq[0][r_][0];
#pragma unroll
    for (int k = 0; k < 4; ++k) d[ul + 128 * k] = rv[k];
  }
#pragma unroll
  for (int k = 0; k < 4; ++k) rv[k] = gb[512 + ul + 128 * k];  // chunk 1 held
  __syncthreads();

  const bool b1 = (p & 1) != 0, b2 = (p & 2) != 0, b4 = (p & 4) != 0;

  for (int c = 0; c < 32; ++c) {
    const int cur = c & 1;
    if (c < 31) {  // stage chunk c+1 (regs loaded a full chunk ago)
      uint4* d = (uint4*)&xq[cur ^ 1][r_][0];
#pragma unroll
      for (int k = 0; k < 4; ++k) d[ul + 128 * k] = rv[k];
    }
    if (c < 30) {  // issue loads for chunk c+2
#pragma unroll
      for (int k = 0; k < 4; ++k) rv[k] = gb[(size_t)(c + 2) * 512 + ul + 128 * k];
    }
    if (c > 0) {  // fc drain of chunk c-1 (journal about to be overwritten)
      const int item = tid >> 2, kp = tid & 3;
      const int r2 = item >> 5, c2 = item & 31;
      float v = 0.f;
      const float4* jp = (const float4*)&hhj[r2][c2][kp * 32];
      const float4* fp = (const float4*)&fcwl[kp * 32];
#pragma unroll
      for (int k4 = 0; k4 < 8; ++k4) v = dot4(fp[k4], jp[k4], v);
      v += swz_xor1(v);
      v += swz_xor2(v);
      if (kp == 0) outrow[r2][(c - 1) * 32 + c2] = v;
      __syncthreads();  // drain reads done before new journal writes
    }

#pragma unroll 4
    for (int cc = 0; cc < 32; ++cc) {
      const float* hA = &hbuf[cc & 1][0][p * 12];
      const float* hB = &hbuf[cc & 1][1][p * 12];
      const float4 ha0 = *(const float4*)hA;
      const float4 ha1 = *(const float4*)(hA + 4);
      const float4 hb0 = *(const float4*)hB;
      const float4 hb1 = *(const float4*)(hB + 4);
      const f32x2 al0 = lo2(ha0), ah0 = hi2(ha0), al1 = lo2(ha1), ah1 = hi2(ha1);
      const f32x2 bl0 = lo2(hb0), bh0 = hi2(hb0), bl1 = lo2(hb1), bh1 = hi2(hb1);

#define CHAIN(m)                                                     \
  f32x2 sa_##m = pkmul(lo2(w0_##m), al0);                            \
  sa_##m = pkfma(hi2(w0_##m), ah0, sa_##m);                          \
  sa_##m = pkfma(lo2(w1_##m), al1, sa_##m);                          \
  sa_##m = pkfma(hi2(w1_##m), ah1, sa_##m);                          \
  const float va_##m = sa_##m.x + sa_##m.y;                          \
  f32x2 sb_##m = pkmul(lo2(w0_##m), bl0);                            \
  sb_##m = pkfma(hi2(w0_##m), bh0, sb_##m);                          \
  sb_##m = pkfma(lo2(w1_##m), bl1, sb_##m);                          \
  sb_##m = pkfma(hi2(w1_##m), bh1, sb_##m);                          \
  const float vb_##m = sb_##m.x + sb_##m.y;
      FOREACH_M(CHAIN)
#undef CHAIN

      // 4-stage value-halving butterfly over p (m bit i <- p bit i), row A
      float ka0 = (b1 ? va_1 : va_0) + lane_xor1(b1 ? va_0 : va_1);
      float ka1 = (b1 ? va_3 : va_2) + lane_xor1(b1 ? va_2 : va_3);
      float ka2 = (b1 ? va_5 : va_4) + lane_xor1(b1 ? va_4 : va_5);
      float ka3 = (b1 ? va_7 : va_6) + lane_xor1(b1 ? va_6 : va_7);
      float na0 = (b2 ? ka1 : ka0) + lane_xor2(b2 ? ka0 : ka1);
      float na1 = (b2 ? ka3 : ka2) + lane_xor2(b2 ? ka2 : ka3);
      float qa = (b4 ? na1 : na0) + lane_xor4(b4 ? na0 : na1);
      float vA = qa + lane_xor8(qa);
      // row B
      float kb0 = (b1 ? vb_1 : vb_0) + lane_xor1(b1 ? vb_0 : vb_1);
      float kb1 = (b1 ? vb_3 : vb_2) + lane_xor1(b1 ? vb_2 : vb_3);
      float kb2 = (b1 ? vb_5 : vb_4) + lane_xor1(b1 ? vb_4 : vb_5);
      float kb3 = (b1 ? vb_7 : vb_6) + lane_xor1(b1 ? vb_6 : vb_7);
      float nb0 = (b2 ? kb1 : kb0) + lane_xor2(b2 ? kb0 : kb1);
      float nb1 = (b2 ? kb3 : kb2) + lane_xor2(b2 ? kb2 : kb3);
      float qb = (b4 ? nb1 : nb0) + lane_xor4(b4 ? nb0 : nb1);
      float vB = qb + lane_xor8(qb);

      const float xA = (float)xq[cur][0][cc * kH + jfin];
      const float xB = (float)xq[cur][1][cc * kH + jfin];
      const float hnA = fast_tanh(vA + xA);
      const float hnB = fast_tanh(vB + xB);

      hbuf[(cc & 1) ^ 1][0][haddr] = hnA;  // dup lanes write same value: benign
      hbuf[(cc & 1) ^ 1][1][haddr] = hnB;
      if (p < 8) {
        hhj[0][cc][slot] = hnA;
        hhj[1][cc][slot] = hnB;
      }
      __syncthreads();
    }
  }

  // final fc drain (chunk 31)
  {
    const int item = tid >> 2, kp = tid & 3;
    const int r2 = item >> 5, c2 = item & 31;
    float v = 0.f;
    const float4* jp = (const float4*)&hhj[r2][c2][kp * 32];
    const float4* fp = (const float4*)&fcwl[kp * 32];
#pragma unroll
    for (int k4 = 0; k4 < 8; ++k4) v = dot4(fp[k4], jp[k4], v);
    v += swz_xor1(v);
    v += swz_xor2(v);
    if (kp == 0) outrow[r2][992 + c2] = v;
  }
  __syncthreads();

  const float fcb0 = fcb[0];
#pragma unroll
  for (int e = 0; e < 8; ++e) {
    const int idx = tid + 256 * e;
    const int r2 = idx >> 10, t0 = idx & 1023;
    float v = outrow[r2][t0];
    if (dir == 0) v += fcb0;
    const int td = dir ? (kS - 1 - t0) : t0;
    atomicAdd(&out[(size_t)(b0 + r2) * kS + td], v);
  }
}

#undef FOREACH_M

}  // namespace

extern "C" void kernel_launch(void* const* d_in, const int* in_sizes, int n_in,
                              void* d_out, int out_size, void* d_ws, size_t ws_size,
                              hipStream_t stream) {
  (void)in_sizes; (void)n_in; (void)ws_size;
  const float* inputs = (const float*)d_in[0];
  const float* Wih_fw = (const float*)d_in[1];
  const float* Whh_fw = (const float*)d_in[2];
  const float* bih_fw = (const float*)d_in[3];
  const float* bhh_fw = (const float*)d_in[4];
  const float* Wih_bw = (const float*)d_in[5];
  const float* Whh_bw = (const float*)d_in[6];
  const float* bih_bw = (const float*)d_in[7];
  const float* bhh_bw = (const float*)d_in[8];
  const float* fc_W   = (const float*)d_in[9];
  const float* fc_b   = (const float*)d_in[10];
  float* out = (float*)d_out;
  _Float16* xp = (_Float16*)d_ws;  // 2*256*1024*128 f16 = 128 MiB

  hipMemsetAsync(out, 0, (size_t)out_size * sizeof(float), stream);

  hipLaunchKernelGGL(xproj_kernel, dim3(256), dim3(256), 0, stream,
                     inputs, Wih_fw, bih_fw, bhh_fw, Wih_bw, bih_bw, bhh_bw, xp);
  hipLaunchKernelGGL(birnn_step_kernel, dim3(256), dim3(256), 0, stream,
                     xp, Whh_fw, Whh_bw, fc_W, fc_b, out);
}

// Round 6
// 570.582 us; speedup vs baseline: 1.5518x; 1.3948x over previous
//
#include <hip/hip_runtime.h>

namespace {

constexpr int kS = 1024;
constexpr int kD = 64;
constexpr int kH = 128;

typedef __attribute__((ext_vector_type(2))) _Float16 half2v;
typedef __attribute__((ext_vector_type(4))) float f32x4;
typedef __attribute__((ext_vector_type(8))) _Float16 half8;

__device__ __forceinline__ float fdot2(unsigned w, unsigned h, float acc) {
#if __has_builtin(__builtin_amdgcn_fdot2)
  return __builtin_amdgcn_fdot2(__builtin_bit_cast(half2v, w),
                                __builtin_bit_cast(half2v, h), acc, false);
#else
  float d;
  asm("v_dot2_f32_f16 %0, %1, %2, %3" : "=v"(d) : "v"(w), "v"(h), "v"(acc));
  return d;
#endif
}

// RNE f16 pack (cvt_pkrtz is RTZ -> systematic shrink bias over 1024 steps)
__device__ __forceinline__ unsigned pk16(float a, float b) {
  half2v h;
  h.x = (_Float16)a;
  h.y = (_Float16)b;
  return __builtin_bit_cast(unsigned, h);
}

__device__ __forceinline__ float fast_tanh(float x) {
  x = fminf(fmaxf(x, -15.f), 15.f);
  float e = __expf(2.f * x);
  return (e - 1.f) * __builtin_amdgcn_rcpf(e + 1.f);
}

#if __has_builtin(__builtin_amdgcn_mov_dpp)
__device__ __forceinline__ float lane_xor1(float v) {
  return __int_as_float(__builtin_amdgcn_mov_dpp(__float_as_int(v), 0xB1, 0xF, 0xF, true));
}
#else
__device__ __forceinline__ float lane_xor1(float v) {
  return __int_as_float(__builtin_amdgcn_ds_swizzle(__float_as_int(v), 0x041F));
}
#endif

// async global->LDS: 8 x 16B/lane = one 8 KB xp chunk (no VGPR round-trip)
__device__ __forceinline__ void stage_chunk(const char* g, unsigned* lds, int L) {
#pragma unroll
  for (int k = 0; k < 8; ++k) {
    __builtin_amdgcn_global_load_lds(
        (const __attribute__((address_space(1))) void*)(g + k * 1024 + L * 16),
        (__attribute__((address_space(3))) void*)(lds + k * 256), 16, 0, 0);
  }
}

// xp (f16) layout per (dir,b) slab of kS*kH elems, chunk-transposed:
//   idx = (t>>5)*(32*kH) + (t&31)*kH + j     (dir=1 pre-time-reversed)
// -> one 32-step chunk = 8 KB contiguous, DMA-stageable.

// =====================  Phase A: x-projection via f16 MFMA  =====================
// (unchanged from R5: 84 us, correct)
__global__ __launch_bounds__(256, 2) void xproj_kernel(
    const float* __restrict__ inputs,
    const float* __restrict__ Wih_fw, const float* __restrict__ bih_fw,
    const float* __restrict__ bhh_fw,
    const float* __restrict__ Wih_bw, const float* __restrict__ bih_bw,
    const float* __restrict__ bhh_bw,
    _Float16* __restrict__ xp) {
  __shared__ _Float16 Wl[256 * 80];
  __shared__ _Float16 xl[128 * 80];
  __shared__ float biasl[256];

  const int tid = threadIdx.x;
  const int b = blockIdx.x;
  const int w = tid >> 6;
  const int lane = tid & 63;
  const int n16 = lane & 15;
  const int q = lane >> 4;

  {
    const int jd = tid;
    const float* src = (jd < kH) ? (Wih_fw + jd * kD) : (Wih_bw + (jd - kH) * kD);
    const float4* s4 = (const float4*)src;
#pragma unroll
    for (int k = 0; k < 8; ++k) {
      float4 a = s4[2 * k], c = s4[2 * k + 1];
      half8 h;
      h[0] = (_Float16)a.x; h[1] = (_Float16)a.y; h[2] = (_Float16)a.z; h[3] = (_Float16)a.w;
      h[4] = (_Float16)c.x; h[5] = (_Float16)c.y; h[6] = (_Float16)c.z; h[7] = (_Float16)c.w;
      *(half8*)&Wl[jd * 80 + k * 8] = h;
    }
    biasl[jd] = (jd < kH) ? (bih_fw[jd] + bhh_fw[jd])
                          : (bih_bw[jd - kH] + bhh_bw[jd - kH]);
  }

  for (int ch = 0; ch < 8; ++ch) {
    __syncthreads();
    {
      const int tl = tid >> 1, hf = tid & 1;
      const float4* s4 = (const float4*)(inputs +
          ((size_t)b * kS + ch * 128 + tl) * kD + hf * 32);
#pragma unroll
      for (int k = 0; k < 4; ++k) {
        float4 a = s4[2 * k], c = s4[2 * k + 1];
        half8 h;
        h[0] = (_Float16)a.x; h[1] = (_Float16)a.y; h[2] = (_Float16)a.z; h[3] = (_Float16)a.w;
        h[4] = (_Float16)c.x; h[5] = (_Float16)c.y; h[6] = (_Float16)c.z; h[7] = (_Float16)c.w;
        *(half8*)&xl[tl * 80 + hf * 32 + k * 8] = h;
      }
    }
    __syncthreads();

    half8 bf0[4], bf1[4];
    float bs[4];
#pragma unroll
    for (int nn = 0; nn < 4; ++nn) {
      const int jd = (w * 4 + nn) * 16 + n16;
      bf0[nn] = *(const half8*)&Wl[jd * 80 + q * 8];
      bf1[nn] = *(const half8*)&Wl[jd * 80 + q * 8 + 32];
      bs[nn] = biasl[jd];
    }

#pragma unroll 2
    for (int m = 0; m < 8; ++m) {
      const int trow = m * 16 + n16;
      const half8 a0 = *(const half8*)&xl[trow * 80 + q * 8];
      const half8 a1 = *(const half8*)&xl[trow * 80 + q * 8 + 32];
#pragma unroll
      for (int nn = 0; nn < 4; ++nn) {
        f32x4 acc = {0.f, 0.f, 0.f, 0.f};
        acc = __builtin_amdgcn_mfma_f32_16x16x32_f16(a0, bf0[nn], acc, 0, 0, 0);
        acc = __builtin_amdgcn_mfma_f32_16x16x32_f16(a1, bf1[nn], acc, 0, 0, 0);
        const int jd = (w * 4 + nn) * 16 + n16;
        const int dir = jd >> 7, j = jd & 127;
        const size_t slab = (size_t)(dir * 256 + b) * (kS * kH);
#pragma unroll
        for (int r = 0; r < 4; ++r) {
          const int t = ch * 128 + m * 16 + q * 4 + r;
          const int tt = dir ? (kS - 1 - t) : t;
          xp[slab + (size_t)(tt >> 5) * (32 * kH) + (tt & 31) * kH + j] =
              (_Float16)(acc[r] + bs[nn]);
        }
      }
    }
  }
}

// =====================  Phase B: wave-autonomous recurrence  =====================
// 512 blocks x 64 threads (ONE wave): dir = blockIdx>>8, b = blockIdx&255.
// Lane L finalizes j0=2L, j1=2L+1 with FULL K=128: no reduction, no barrier.
// h ring jrn[32 rows][64 dw + pad4]: dword k = (h_2k, h_2k+1) f16 — serves both
// the per-step broadcast (16 uniform ds_read_b128, conflict-free) and the fc
// journal. Weights: 128 packed-f16 dwords/lane, consumed by v_dot2_f32_f16.
// xp chunks DMA'd via global_load_lds, one vmcnt gate per 32 steps.
__global__ __launch_bounds__(64, 1) void birnn_step_kernel(
    const _Float16* __restrict__ xp,
    const float* __restrict__ Whh_fw, const float* __restrict__ Whh_bw,
    const float* __restrict__ fcW, const float* __restrict__ fcb,
    float* __restrict__ out) {
  const int dir = blockIdx.x >> 8;
  const int b = blockIdx.x & 255;
  const int L = threadIdx.x;

  __shared__ unsigned jrn[32 * 68];   // 68-dw rows: b128-aligned, 2-way max
  __shared__ unsigned xbuf[2][2048];  // two 8 KB xp chunks
  __shared__ unsigned fcwl[64];       // fc weights, packed f16 pairs
  __shared__ float outbuf[kS];

  const float* __restrict__ Whh = dir ? Whh_bw : Whh_fw;

  // ---- weights: rows j0,j1 -> 128 packed-f16 dwords (w[k]=(W[j][2k],W[j][2k+1]))
  unsigned w0[64], w1[64];
  {
    const float* r0 = Whh + (size_t)(2 * L) * kH;
    const float* r1 = Whh + (size_t)(2 * L + 1) * kH;
#pragma unroll
    for (int k = 0; k < 64; ++k) {
      w0[k] = pk16(r0[2 * k], r0[2 * k + 1]);
      w1[k] = pk16(r1[2 * k], r1[2 * k + 1]);
    }
  }
  fcwl[L] = pk16(fcW[dir * kH + 2 * L], fcW[dir * kH + 2 * L + 1]);
  jrn[31 * 68 + L] = 0;  // h_{-1} = 0

  // ---- prime xp chunks 0,1 ----
  const char* slab = (const char*)(xp + (size_t)(dir * 256 + b) * (kS * kH));
  stage_chunk(slab, &xbuf[0][0], L);
  stage_chunk(slab + 8192, &xbuf[1][0], L);
  asm volatile("s_waitcnt vmcnt(0)" ::: "memory");

  for (int c = 0; c < 32; ++c) {
    const unsigned* xb = &xbuf[c & 1][0];

#pragma unroll 2
    for (int s = 0; s < 32; ++s) {
      const int prev = (s + 31) & 31;
      const uint4* hr = (const uint4*)&jrn[prev * 68];
      float a0 = 0.f, a1 = 0.f, a2 = 0.f, a3 = 0.f;
      float c0 = 0.f, c1 = 0.f, c2 = 0.f, c3 = 0.f;
#pragma unroll
      for (int g = 0; g < 16; ++g) {
        const uint4 hv = hr[g];
        a0 = fdot2(w0[4 * g + 0], hv.x, a0);
        c0 = fdot2(w1[4 * g + 0], hv.x, c0);
        a1 = fdot2(w0[4 * g + 1], hv.y, a1);
        c1 = fdot2(w1[4 * g + 1], hv.y, c1);
        a2 = fdot2(w0[4 * g + 2], hv.z, a2);
        c2 = fdot2(w1[4 * g + 2], hv.z, c2);
        a3 = fdot2(w0[4 * g + 3], hv.w, a3);
        c3 = fdot2(w1[4 * g + 3], hv.w, c3);
      }
      const half2v xh = __builtin_bit_cast(half2v, xb[s * 64 + L]);
      const float va = ((a0 + a1) + (a2 + a3)) + (float)xh.x;
      const float vb = ((c0 + c1) + (c2 + c3)) + (float)xh.y;
      jrn[s * 68 + L] = pk16(fast_tanh(va), fast_tanh(vb));
    }

    // ---- fc drain of chunk c (rows about to be reused next chunk) ----
    {
      const int tl = L >> 1, jh = L & 1;
      const uint4* rp = (const uint4*)&jrn[tl * 68 + jh * 32];
      const uint4* fp = (const uint4*)&fcwl[jh * 32];
      float acc = 0.f;
#pragma unroll
      for (int k = 0; k < 8; ++k) {
        const uint4 hv = rp[k];
        const uint4 fw = fp[k];
        acc = fdot2(fw.x, hv.x, acc);
        acc = fdot2(fw.y, hv.y, acc);
        acc = fdot2(fw.z, hv.z, acc);
        acc = fdot2(fw.w, hv.w, acc);
      }
      acc += lane_xor1(acc);
      if (jh == 0) outbuf[c * 32 + tl] = acc;
    }

    // ---- stage chunk c+2 into the buffer just freed; gate chunk c+1 ----
    if (c < 30) {
      stage_chunk(slab + (size_t)(c + 2) * 8192, &xbuf[c & 1][0], L);
      asm volatile("s_waitcnt vmcnt(8)" ::: "memory");
    } else if (c == 30) {
      asm volatile("s_waitcnt vmcnt(0)" ::: "memory");
    }
  }

  // ---- emit: one atomic pass (fw adds fcb) ----
  const float fcb0 = (dir == 0) ? fcb[0] : 0.f;
#pragma unroll
  for (int k = 0; k < 16; ++k) {
    const int t = L + 64 * k;
    const int td = dir ? (kS - 1 - t) : t;
    atomicAdd(&out[(size_t)b * kS + td], outbuf[t] + fcb0);
  }
}

}  // namespace

extern "C" void kernel_launch(void* const* d_in, const int* in_sizes, int n_in,
                              void* d_out, int out_size, void* d_ws, size_t ws_size,
                              hipStream_t stream) {
  (void)in_sizes; (void)n_in; (void)ws_size;
  const float* inputs = (const float*)d_in[0];
  const float* Wih_fw = (const float*)d_in[1];
  const float* Whh_fw = (const float*)d_in[2];
  const float* bih_fw = (const float*)d_in[3];
  const float* bhh_fw = (const float*)d_in[4];
  const float* Wih_bw = (const float*)d_in[5];
  const float* Whh_bw = (const float*)d_in[6];
  const float* bih_bw = (const float*)d_in[7];
  const float* bhh_bw = (const float*)d_in[8];
  const float* fc_W   = (const float*)d_in[9];
  const float* fc_b   = (const float*)d_in[10];
  float* out = (float*)d_out;
  _Float16* xpw = (_Float16*)d_ws;  // 2*256*1024*128 f16 = 128 MiB

  hipMemsetAsync(out, 0, (size_t)out_size * sizeof(float), stream);

  hipLaunchKernelGGL(xproj_kernel, dim3(256), dim3(256), 0, stream,
                     inputs, Wih_fw, bih_fw, bhh_fw, Wih_bw, bih_bw, bhh_bw, xpw);
  hipLaunchKernelGGL(birnn_step_kernel, dim3(512), dim3(64), 0, stream,
                     xpw, Whh_fw, Whh_bw, fc_W, fc_b, out);
}